// Round 6
// baseline (53.731 us; speedup 1.0000x reference)
//
#include <hip/hip_runtime.h>
#include <hip/hip_bf16.h>

#define NN 256
#define VC 32
#define FD 128

typedef unsigned int uint32;
typedef unsigned short u16;
typedef __attribute__((ext_vector_type(8))) short bf16x8;
typedef __attribute__((ext_vector_type(4))) float f32x4;

__device__ __forceinline__ float selu_f(float x) {
    const float lam = 1.0507009873554805f;
    const float la  = 1.7580993408473766f;
    return x > 0.f ? lam * x : la * (__expf(x) - 1.f);
}

__device__ __forceinline__ u16 f32_to_bf16_rne(float f) {
    uint32 u = __float_as_uint(f);
    uint32 r = (u + 0x7fffu + ((u >> 16) & 1u)) >> 16;
    return (u16)r;
}

__device__ __forceinline__ float bf16_to_f32(u16 h) {
    return __uint_as_float(((uint32)h) << 16);
}

// ---------------------------------------------------------------- K1: node precompute + weight repack
__global__ __launch_bounds__(256) void k1_pre(
    const float* __restrict__ feat, const float* __restrict__ We1,
    const float* __restrict__ be1, const float* __restrict__ Wq,
    const float* __restrict__ Wk, const float* __restrict__ Wv,
    const float* __restrict__ Wvec, const float* __restrict__ We2,
    const float* __restrict__ pos,
    float* __restrict__ A, float* __restrict__ Bf, u16* __restrict__ kqb,
    u16* __restrict__ w1b, u16* __restrict__ we2b, u16* __restrict__ wvb,
    u16* __restrict__ fvtH, u16* __restrict__ fvtL,
    u16* __restrict__ ptH, u16* __restrict__ ptL,
    float* __restrict__ lgg2, u16* __restrict__ cfg2)
{
    __shared__ float fl[FD];
    __shared__ float ql[FD];
    const int n = blockIdx.x;
    const int t = threadIdx.x;
    // ---- weight repack, spread across all blocks (1 elem/thread)
    {
        const int gid = n*256 + t;
        if (gid < 16384) {
            const int c = gid >> 8, k = gid & 255;
            w1b[gid] = f32_to_bf16_rne(We1[(256 + k)*64 + c]);
        } else if (gid < 20480) {
            const int o = gid - 16384;
            const int c = o >> 6, k = o & 63;
            we2b[o] = f32_to_bf16_rne(We2[k*64 + c]);
        } else if (gid < 22528) {
            const int o = gid - 20480;
            const int v = o >> 6, k = o & 63;
            wvb[o] = f32_to_bf16_rne(Wvec[k*32 + v]);
        }
    }
    if (t < FD) fl[t] = feat[n*FD + t];
    __syncthreads();
    if (t < 64) {
        float a = 0.f;
        for (int i = 0; i < FD; ++i) a = fmaf(fl[i], We1[i*64 + t], a);
        A[n*64 + t] = a;
    } else if (t < 128) {
        const int j = t - 64;
        float a = be1[j];
        for (int i = 0; i < FD; ++i) a = fmaf(fl[i], We1[(FD+i)*64 + j], a);
        Bf[n*64 + j] = a;
    } else {
        const int j = t - 128;
        float a = 0.f;
        for (int i = 0; i < FD; ++i) a = fmaf(fl[i], Wq[i*FD + j], a);
        ql[j] = a * 0.25f;   // fold 1/sqrt(DH)
    }
    if (t < FD) {
        float a = 0.f;
        for (int i = 0; i < FD; ++i) a = fmaf(fl[i], Wv[i*FD + t], a);
        const u16 hi = f32_to_bf16_rne(a);
        const u16 lo = f32_to_bf16_rne(a - bf16_to_f32(hi));
        fvtH[t*256 + n] = hi;
        fvtL[t*256 + n] = lo;
    }
    if (t < 128) {   // posT [32v][4c][256s] hi/lo, col3 = 1.0
        const int v = t >> 2, c = t & 3;
        const float val = (c < 3) ? pos[(n*VC + v)*3 + c] : 1.0f;
        const u16 hi = f32_to_bf16_rne(val);
        const u16 lo = f32_to_bf16_rne(val - bf16_to_f32(hi));
        ptH[(v*4+c)*256 + n] = hi;
        ptL[(v*4+c)*256 + n] = lo;
    }
    // diagonal init (self-edge excluded)
    if (t < 8)  lgg2[n*2048 + t*256 + n] = -1e30f;
    if (t < 32) cfg2[n*8192 + t*256 + n] = 0;
    __syncthreads();
    for (int o = t; o < 512; o += 256) {   // kqb[n][h][j]
        const int h = o >> 6, j = o & 63;
        float a = 0.f;
        #pragma unroll
        for (int d = 0; d < 16; ++d)
            a = fmaf(Wk[j*FD + h*16 + d], ql[h*16 + d], a);
        kqb[n*512 + o] = f32_to_bf16_rne(a);
    }
}

// ---------------------------------------------------------------- K2: edge pipeline (MFMA)
// 1024 blocks: r = b>>2, part = b&3, 2 tiles of 32 senders each.
__global__ __launch_bounds__(256) void k2_edge(
    const float* __restrict__ pos, const float* __restrict__ be2,
    const float* __restrict__ Ag, const float* __restrict__ Bfg,
    const u16* __restrict__ w1b, const u16* __restrict__ we2b,
    const u16* __restrict__ wvb, const u16* __restrict__ kqb,
    float* __restrict__ lgg2, u16* __restrict__ cfg2)
{
    __shared__ u16 rad[8192];       // [32e][32v][8b] bf16, xor-swizzled (16KB)
    __shared__ u16 h1b[32*64];
    __shared__ u16 h2b[32*64];
    __shared__ float invl[32*33];

    const int t = threadIdx.x;
    const int wave = t >> 6, l = t & 63;
    const int li = l & 15, q = l >> 4;
    const int mh = wave >> 1, eh = wave & 1;
    const int r = blockIdx.x >> 2, part = blockIdx.x & 3;
    const int e = eh*16 + li;
    const int swz16 = (e & 7) << 3;   // u16-index xor for h1b/h2b

    // ---- weight fragments (single 16B loads)
    bf16x8 w1A[2][8];
    #pragma unroll
    for (int mt = 0; mt < 2; ++mt) {
        const int c = mh*32 + mt*16 + li;
        #pragma unroll
        for (int kb = 0; kb < 8; ++kb)
            w1A[mt][kb] = *(const bf16x8*)(w1b + c*256 + kb*32 + q*8);
    }
    bf16x8 we2A[2][2];
    #pragma unroll
    for (int mt = 0; mt < 2; ++mt) {
        const int c2 = mh*32 + mt*16 + li;
        #pragma unroll
        for (int kb = 0; kb < 2; ++kb)
            we2A[mt][kb] = *(const bf16x8*)(we2b + c2*64 + kb*32 + q*8);
    }
    bf16x8 wvA[2];
    {
        const int v = mh*16 + li;
        #pragma unroll
        for (int kb = 0; kb < 2; ++kb)
            wvA[kb] = *(const bf16x8*)(wvb + v*64 + kb*32 + q*8);
    }
    bf16x8 kqA[2];
    if (li < 8) {
        #pragma unroll
        for (int kb = 0; kb < 2; ++kb)
            kqA[kb] = *(const bf16x8*)(kqb + r*512 + li*64 + kb*32 + q*8);
    } else {
        #pragma unroll
        for (int kb = 0; kb < 2; ++kb)
            #pragma unroll
            for (int j = 0; j < 8; ++j) kqA[kb][j] = 0;
    }
    float bfreg[2][4], be2reg[2][4];
    #pragma unroll
    for (int mt = 0; mt < 2; ++mt)
        #pragma unroll
        for (int rg = 0; rg < 4; ++rg) {
            const int c = mh*32 + mt*16 + q*4 + rg;
            bfreg[mt][rg] = Bfg[r*64 + c];
            be2reg[mt][rg] = be2[c];
        }

    for (int it = 0; it < 2; ++it) {
        const int s0 = (part*2 + it) * 32;
        const int sp = s0 + e;
        int s = sp + (sp >= r ? 1 : 0); if (s > 255) s = 255;
        __syncthreads();    // protect LDS reuse from previous tile

        // prefetch per-edge bias rows (latency overlaps P0)
        float As[2][4];
        #pragma unroll
        for (int mt = 0; mt < 2; ++mt)
            #pragma unroll
            for (int rg = 0; rg < 4; ++rg)
                As[mt][rg] = Ag[s*64 + mh*32 + mt*16 + q*4 + rg];

        // ---- P0: radial basis -> swizzled LDS (each thread 4 (e,v) pairs, no redundancy)
        {
            const int ep = t & 31, vg = t >> 5;
            const int spp = s0 + ep;
            int sv = spp + (spp >= r ? 1 : 0); if (sv > 255) sv = 255;
            #pragma unroll
            for (int kk = 0; kk < 4; ++kk) {
                const int v = vg*4 + kk;
                const float* ps = pos + (sv*VC + v)*3;
                const float* pr = pos + (r*VC + v)*3;
                const float dx = ps[0]-pr[0], dy = ps[1]-pr[1], dz = ps[2]-pr[2];
                const float d2 = fmaf(dx,dx,fmaf(dy,dy,dz*dz)) + 1e-18f;
                const float len = sqrtf(d2);
                invl[ep*33 + v] = rsqrtf(d2);
                const float x = fmaxf(len, 1e-6f);
                const float tt2 = 2.f - 0.4f*len;
                const float env = tt2 > 0.f ? 1.9784655248401538f * __expf(-1.f/tt2) : 0.f;
                const float coefc = 0.6324555320336759f * env / x;
                float s_cur, c1;
                __sincosf(0.6283185307179586f * x, &s_cur, &c1);
                const float c2x = 2.f * c1;
                float s_prev = 0.f;
                union { uint4 u4; u16 us[8]; } pk;
                #pragma unroll
                for (int b = 0; b < 8; ++b) {
                    pk.us[b] = f32_to_bf16_rne(coefc * s_cur);
                    const float s_next = fmaf(c2x, s_cur, -s_prev);
                    s_prev = s_cur; s_cur = s_next;
                }
                *(uint4*)((char*)rad + ((ep*512 + v*16) ^ ((ep & 15) << 4))) = pk.u4;
            }
        }
        __syncthreads();    // rad/invl ready

        // ---- GEMM1: h1[c][e] = radial @ We1_rad (+A[s]+Bf[r]) -> selu -> LDS bf16
        f32x4 d1[2] = {{0.f,0.f,0.f,0.f},{0.f,0.f,0.f,0.f}};
        #pragma unroll
        for (int kb = 0; kb < 8; ++kb) {
            const bf16x8 rf = *(const bf16x8*)((const char*)rad +
                                ((e*512 + (kb*4+q)*16) ^ ((e & 15) << 4)));
            d1[0] = __builtin_amdgcn_mfma_f32_16x16x32_bf16(w1A[0][kb], rf, d1[0], 0, 0, 0);
            d1[1] = __builtin_amdgcn_mfma_f32_16x16x32_bf16(w1A[1][kb], rf, d1[1], 0, 0, 0);
        }
        #pragma unroll
        for (int mt = 0; mt < 2; ++mt) {
            const int c0 = mh*32 + mt*16 + q*4;
            const u16 p0 = f32_to_bf16_rne(selu_f(d1[mt][0] + As[mt][0] + bfreg[mt][0]));
            const u16 p1 = f32_to_bf16_rne(selu_f(d1[mt][1] + As[mt][1] + bfreg[mt][1]));
            const u16 p2 = f32_to_bf16_rne(selu_f(d1[mt][2] + As[mt][2] + bfreg[mt][2]));
            const u16 p3 = f32_to_bf16_rne(selu_f(d1[mt][3] + As[mt][3] + bfreg[mt][3]));
            *(uint32*)&h1b[e*64 + ((c0)     ^ swz16)] = (uint32)p0 | ((uint32)p1 << 16);
            *(uint32*)&h1b[e*64 + ((c0 + 2) ^ swz16)] = (uint32)p2 | ((uint32)p3 << 16);
        }
        __syncthreads();

        // ---- GEMM2: h2 = selu(h1 @ We2 + be2)
        f32x4 d2[2] = {{0.f,0.f,0.f,0.f},{0.f,0.f,0.f,0.f}};
        #pragma unroll
        for (int kb = 0; kb < 2; ++kb) {
            const bf16x8 hb = *(const bf16x8*)&h1b[e*64 + ((kb*32 + q*8) ^ swz16)];
            d2[0] = __builtin_amdgcn_mfma_f32_16x16x32_bf16(we2A[0][kb], hb, d2[0], 0, 0, 0);
            d2[1] = __builtin_amdgcn_mfma_f32_16x16x32_bf16(we2A[1][kb], hb, d2[1], 0, 0, 0);
        }
        #pragma unroll
        for (int mt = 0; mt < 2; ++mt) {
            const int c0 = mh*32 + mt*16 + q*4;
            const u16 p0 = f32_to_bf16_rne(selu_f(d2[mt][0] + be2reg[mt][0]));
            const u16 p1 = f32_to_bf16_rne(selu_f(d2[mt][1] + be2reg[mt][1]));
            const u16 p2 = f32_to_bf16_rne(selu_f(d2[mt][2] + be2reg[mt][2]));
            const u16 p3 = f32_to_bf16_rne(selu_f(d2[mt][3] + be2reg[mt][3]));
            *(uint32*)&h2b[e*64 + ((c0)     ^ swz16)] = (uint32)p0 | ((uint32)p1 << 16);
            *(uint32*)&h2b[e*64 + ((c0 + 2) ^ swz16)] = (uint32)p2 | ((uint32)p3 << 16);
        }
        __syncthreads();

        // ---- GEMM3 (coeff) + logit MFMA
        f32x4 d3 = {0.f,0.f,0.f,0.f};
        f32x4 dl = {0.f,0.f,0.f,0.f};
        #pragma unroll
        for (int kb = 0; kb < 2; ++kb) {
            const bf16x8 hb = *(const bf16x8*)&h2b[e*64 + ((kb*32 + q*8) ^ swz16)];
            d3 = __builtin_amdgcn_mfma_f32_16x16x32_bf16(wvA[kb], hb, d3, 0, 0, 0);
            if (mh == 0)
                dl = __builtin_amdgcn_mfma_f32_16x16x32_bf16(kqA[kb], hb, dl, 0, 0, 0);
        }
        if (sp < 255) {
            // cfg2[r][v][s] = coeff * sqrt3 / len   (node-space)
            #pragma unroll
            for (int rg = 0; rg < 4; ++rg) {
                const int v = mh*16 + q*4 + rg;
                cfg2[(size_t)r*8192 + v*256 + s] =
                    f32_to_bf16_rne(d3[rg] * 1.7320508075688772f * invl[e*33 + v]);
            }
            // lgg2[r][h][s]
            if (mh == 0 && q < 2) {
                #pragma unroll
                for (int rg = 0; rg < 4; ++rg)
                    lgg2[(size_t)r*2048 + (q*4+rg)*256 + s] = dl[rg];
            }
        }
    }
}

// ---------------------------------------------------------------- K3b: MFMA aggregations + fused softmax stats
// blocks 0..127: inv (h = b>>4, rtile = b&15). blocks 128..639: vec (v = (b-128)>>4, rtile = (b-128)&15).
__global__ __launch_bounds__(64) void k3b_agg(
    const float* __restrict__ lgg2, const u16* __restrict__ cfg2,
    const u16* __restrict__ fvtH, const u16* __restrict__ fvtL,
    const u16* __restrict__ ptH, const u16* __restrict__ ptL,
    float* __restrict__ inv, float* __restrict__ vec4)
{
    const int l = threadIdx.x, li = l & 15, q = l >> 4;
    const int b = blockIdx.x;
    if (b < 128) {
        const int h = b >> 4, r0 = (b & 15) * 16;
        bf16x8 fH[8], fL[8];
        #pragma unroll
        for (int kb = 0; kb < 8; ++kb) {
            fH[kb] = *(const bf16x8*)(fvtH + (h*16+li)*256 + kb*32 + q*8);
            fL[kb] = *(const bf16x8*)(fvtL + (h*16+li)*256 + kb*32 + q*8);
        }
        const float* lgr = lgg2 + (size_t)(r0+li)*2048 + h*256;
        // pass 1: row max (row = r0+li), reduce over q-lanes
        float mx = -3.0e38f;
        #pragma unroll
        for (int kb = 0; kb < 8; ++kb) {
            const float4 g0 = *(const float4*)(lgr + kb*32 + q*8);
            const float4 g1 = *(const float4*)(lgr + kb*32 + q*8 + 4);
            mx = fmaxf(mx, fmaxf(fmaxf(g0.x,g0.y), fmaxf(g0.z,g0.w)));
            mx = fmaxf(mx, fmaxf(fmaxf(g1.x,g1.y), fmaxf(g1.z,g1.w)));
        }
        mx = fmaxf(mx, __shfl_xor(mx, 16));
        mx = fmaxf(mx, __shfl_xor(mx, 32));
        // pass 2: exp + MFMA (dual accumulators break the dep chain) + denom
        float sm = 0.f;
        f32x4 Ch = {0.f,0.f,0.f,0.f};
        f32x4 Cl = {0.f,0.f,0.f,0.f};
        #pragma unroll
        for (int kb = 0; kb < 8; ++kb) {
            const float4 g0 = *(const float4*)(lgr + kb*32 + q*8);
            const float4 g1 = *(const float4*)(lgr + kb*32 + q*8 + 4);
            float ev[8];
            ev[0]=__expf(g0.x-mx); ev[1]=__expf(g0.y-mx); ev[2]=__expf(g0.z-mx); ev[3]=__expf(g0.w-mx);
            ev[4]=__expf(g1.x-mx); ev[5]=__expf(g1.y-mx); ev[6]=__expf(g1.z-mx); ev[7]=__expf(g1.w-mx);
            bf16x8 a;
            #pragma unroll
            for (int j = 0; j < 8; ++j) { sm += ev[j]; a[j] = (short)f32_to_bf16_rne(ev[j]); }
            Ch = __builtin_amdgcn_mfma_f32_16x16x32_bf16(a, fH[kb], Ch, 0, 0, 0);
            Cl = __builtin_amdgcn_mfma_f32_16x16x32_bf16(a, fL[kb], Cl, 0, 0, 0);
        }
        sm += __shfl_xor(sm, 16);
        sm += __shfl_xor(sm, 32);
        #pragma unroll
        for (int rg = 0; rg < 4; ++rg) {
            const float d = __shfl(sm, q*4 + rg);
            inv[(r0 + q*4 + rg)*128 + h*16 + li] = (Ch[rg] + Cl[rg]) / (d + 1e-12f);
        }
    } else {
        const int b2 = b - 128, v = b2 >> 4, r0 = (b2 & 15) * 16;
        const int h = v >> 2;
        bf16x8 pH[8], pL[8];
        #pragma unroll
        for (int kb = 0; kb < 8; ++kb) {
            if (li < 4) {
                pH[kb] = *(const bf16x8*)(ptH + (v*4+li)*256 + kb*32 + q*8);
                pL[kb] = *(const bf16x8*)(ptL + (v*4+li)*256 + kb*32 + q*8);
            } else {
                #pragma unroll
                for (int j = 0; j < 8; ++j) { pH[kb][j] = 0; pL[kb][j] = 0; }
            }
        }
        const float* lgr = lgg2 + (size_t)(r0+li)*2048 + h*256;
        const u16*  cfr = cfg2 + (size_t)(r0+li)*8192 + v*256;
        float mx = -3.0e38f;
        #pragma unroll
        for (int kb = 0; kb < 8; ++kb) {
            const float4 g0 = *(const float4*)(lgr + kb*32 + q*8);
            const float4 g1 = *(const float4*)(lgr + kb*32 + q*8 + 4);
            mx = fmaxf(mx, fmaxf(fmaxf(g0.x,g0.y), fmaxf(g0.z,g0.w)));
            mx = fmaxf(mx, fmaxf(fmaxf(g1.x,g1.y), fmaxf(g1.z,g1.w)));
        }
        mx = fmaxf(mx, __shfl_xor(mx, 16));
        mx = fmaxf(mx, __shfl_xor(mx, 32));
        float sm = 0.f;
        f32x4 Ch = {0.f,0.f,0.f,0.f};
        f32x4 Cl = {0.f,0.f,0.f,0.f};
        #pragma unroll
        for (int kb = 0; kb < 8; ++kb) {
            const float4 g0 = *(const float4*)(lgr + kb*32 + q*8);
            const float4 g1 = *(const float4*)(lgr + kb*32 + q*8 + 4);
            const bf16x8 cf8 = *(const bf16x8*)(cfr + kb*32 + q*8);
            float ev[8];
            ev[0]=__expf(g0.x-mx); ev[1]=__expf(g0.y-mx); ev[2]=__expf(g0.z-mx); ev[3]=__expf(g0.w-mx);
            ev[4]=__expf(g1.x-mx); ev[5]=__expf(g1.y-mx); ev[6]=__expf(g1.z-mx); ev[7]=__expf(g1.w-mx);
            bf16x8 a;
            #pragma unroll
            for (int j = 0; j < 8; ++j) {
                sm += ev[j];
                a[j] = (short)f32_to_bf16_rne(ev[j] * bf16_to_f32((u16)cf8[j]));
            }
            Ch = __builtin_amdgcn_mfma_f32_16x16x32_bf16(a, pH[kb], Ch, 0, 0, 0);
            Cl = __builtin_amdgcn_mfma_f32_16x16x32_bf16(a, pL[kb], Cl, 0, 0, 0);
        }
        sm += __shfl_xor(sm, 16);
        sm += __shfl_xor(sm, 32);
        #pragma unroll
        for (int rg = 0; rg < 4; ++rg) {
            const float d = __shfl(sm, q*4 + rg);
            if (li < 4)
                vec4[(r0 + q*4 + rg)*128 + v*4 + li] = (Ch[rg] + Cl[rg]) / (d + 1e-12f);
        }
    }
}

// ---------------------------------------------------------------- K3c: node MLP + vec combine (1 node/block, 1 wave)
__global__ __launch_bounds__(64) void k3c_out(
    const float* __restrict__ pos, const float* __restrict__ feat,
    const float* __restrict__ inv, const float* __restrict__ vec4,
    const float* __restrict__ Wmix,
    const float* __restrict__ M1, const float* __restrict__ bm1,
    const float* __restrict__ M2, const float* __restrict__ bm2,
    const float* __restrict__ M3, const float* __restrict__ bm3,
    float* __restrict__ out0, float* __restrict__ out1)
{
    __shared__ float inva[128];
    __shared__ float vec4s[128];
    __shared__ float pos96[96];
    __shared__ float vecl[96];
    __shared__ float hi1[64];
    __shared__ float hi2[64];
    const int r = blockIdx.x;
    const int l = threadIdx.x;
    inva[l]       = inv[r*128 + l];
    inva[64 + l]  = inv[r*128 + 64 + l];
    vec4s[l]      = vec4[r*128 + l];
    vec4s[64 + l] = vec4[r*128 + 64 + l];
    for (int o = l; o < 96; o += 64) pos96[o] = pos[r*96 + o];
    __syncthreads();    // single wave: compiles to a cheap barrier
    for (int o = l; o < 96; o += 64) {
        const int v = o / 3, c = o - v*3;
        vecl[o] = vec4s[v*4 + c] - vec4s[v*4 + 3] * pos96[o];
    }
    // stage1: hi1 = selu(inva @ M1 + b1)
    float a1 = bm1[l];
    #pragma unroll 8
    for (int k = 0; k < 128; ++k) a1 = fmaf(inva[k], M1[k*64 + l], a1);
    hi1[l] = selu_f(a1);
    __syncthreads();
    // stage2
    float a2 = bm2[l];
    #pragma unroll 8
    for (int k = 0; k < 64; ++k) a2 = fmaf(hi1[k], M2[k*64 + l], a2);
    hi2[l] = selu_f(a2);
    __syncthreads();
    // stage3 -> out1 (2 outputs/thread)
    #pragma unroll
    for (int o0 = 0; o0 < 128; o0 += 64) {
        const int o = o0 + l;
        float a = bm3[o];
        #pragma unroll 8
        for (int k = 0; k < 64; ++k) a = fmaf(hi2[k], M3[k*128 + o], a);
        out1[r*128 + o] = a + feat[r*128 + o];
    }
    // out0 = vecl @ Wmix + pos
    for (int o = l; o < 96; o += 64) {
        const int w = o / 3, c = o - w*3;
        float a = 0.f;
        #pragma unroll
        for (int v = 0; v < 32; ++v)
            a = fmaf(vecl[v*3 + c], Wmix[v*32 + w], a);
        out0[r*96 + o] = a + pos96[o];
    }
}

extern "C" void kernel_launch(void* const* d_in, const int* in_sizes, int n_in,
                              void* d_out, int out_size, void* d_ws, size_t ws_size,
                              hipStream_t stream)
{
    const float* pos  = (const float*)d_in[0];
    const float* feat = (const float*)d_in[1];
    const float* We1  = (const float*)d_in[2];
    const float* be1  = (const float*)d_in[3];
    const float* We2  = (const float*)d_in[4];
    const float* be2  = (const float*)d_in[5];
    const float* Wq   = (const float*)d_in[6];
    const float* Wk   = (const float*)d_in[7];
    const float* Wv   = (const float*)d_in[8];
    const float* Wvec = (const float*)d_in[9];
    const float* Wmix = (const float*)d_in[10];
    const float* M1   = (const float*)d_in[11];
    const float* bm1  = (const float*)d_in[12];
    const float* M2   = (const float*)d_in[13];
    const float* bm2  = (const float*)d_in[14];
    const float* M3   = (const float*)d_in[15];
    const float* bm3  = (const float*)d_in[16];

    char* ws = (char*)d_ws;
    float* A    = (float*)(ws + 0);        // [256][64]
    float* Bf   = (float*)(ws + 65536);    // [256][64]
    u16*   kqb  = (u16*)(ws + 131072);     // [256][8][64]
    u16*   w1b  = (u16*)(ws + 393216);     // [64][256]
    u16*   we2b = (u16*)(ws + 425984);     // [64][64]
    u16*   wvb  = (u16*)(ws + 434176);     // [32][64]
    u16*   fvtH = (u16*)(ws + 438272);     // [128][256]
    u16*   fvtL = (u16*)(ws + 503808);
    u16*   ptH  = (u16*)(ws + 569344);     // [32][4][256]
    u16*   ptL  = (u16*)(ws + 634880);
    float* lgg2 = (float*)(ws + 700416);   // [256][8][256]
    u16*   cfg2 = (u16*)(ws + 2797568);    // [256][32][256]
    // overlays (region of A/Bf/kqb, dead after k2)
    float* inv   = (float*)(ws + 0);       // [256][128]
    float* vec4  = (float*)(ws + 131072);  // [256][32][4]
    if (ws_size < (size_t)6991872) return;

    float* out0 = (float*)d_out;           // [256][32][3]
    float* out1 = out0 + NN*VC*3;          // [256][128]

    hipLaunchKernelGGL(k1_pre, dim3(256), dim3(256), 0, stream,
                       feat, We1, be1, Wq, Wk, Wv, Wvec, We2, pos,
                       A, Bf, kqb, w1b, we2b, wvb, fvtH, fvtL, ptH, ptL, lgg2, cfg2);
    hipLaunchKernelGGL(k2_edge, dim3(1024), dim3(256), 0, stream,
                       pos, be2, A, Bf, w1b, we2b, wvb, kqb, lgg2, cfg2);
    hipLaunchKernelGGL(k3b_agg, dim3(640), dim3(64), 0, stream,
                       lgg2, cfg2, fvtH, fvtL, ptH, ptL, inv, vec4);
    hipLaunchKernelGGL(k3c_out, dim3(256), dim3(64), 0, stream,
                       pos, feat, inv, vec4, Wmix,
                       M1, bm1, M2, bm2, M3, bm3, out0, out1);
}